// Round 7
// baseline (230.740 us; speedup 1.0000x reference)
//
#include <hip/hip_runtime.h>

#define HOP 256
#define SEG 1024
#define BLOCK 256
#define UNROLL 8

typedef float f32x4 __attribute__((ext_vector_type(4)));

// y[b,i] = x[b,i] * W[pos],  W[pos] = sum_{m=0..3} aw[r+256m]*sw[r+256m]
//   r = pos & 255, blk = pos >> 8, term m included iff blk >= m && blk-m <= kmax.
//
// Round-7 hypothesis: round 3's ILP regression was a LOCALITY artifact (its 8
// in-flight loads were 16 MB apart). This version keeps 8 loads in flight per
// wave but inside a contiguous 32 KB block window: per-wave overlap of the
// ~50% L3-miss read latency with DRAM-row-local bursts.
//  - thread t of block b handles float4s  b*2048 + t + u*256, u=0..7
//  - every load instruction is wave-coalesced (1 KB), all 8 within 32 KB
//  - r = pos & 255 is invariant across u (u*1024 floats == 0 mod 256)
//  - blk varies per u; interior test stays wave-uniform
//  - blocks never straddle a row: 2048 | 2^19 float4s per row
__global__ __launch_bounds__(BLOCK) void SegmenterTensorFlow_28698971472345_kernel(
    const f32x4* __restrict__ x4,
    const float* __restrict__ aw,
    const float* __restrict__ sw,
    f32x4* __restrict__ y4,
    int n_mask,          // N - 1 (N power of two)
    int kmax)            // num_segments - 1 = 8188
{
    const int base = blockIdx.x * (BLOCK * UNROLL) + threadIdx.x;

    // Issue all 8 contiguous bulk loads first: 8 KB in flight per wave,
    // all within the block's 32 KB window.
    f32x4 xv[UNROLL];
#pragma unroll
    for (int u = 0; u < UNROLL; ++u)
        xv[u] = x4[base + u * BLOCK];

    // Combined-window table build overlaps the bulk-load latency (L1/L2-hot).
    __shared__ float wt[HOP];
    {
        const int i = threadIdx.x;
        float acc = 0.f;
#pragma unroll
        for (int m = 0; m < 4; ++m)
            acc += aw[i + m * HOP] * sw[i + m * HOP];
        wt[i] = acc;
    }
    __syncthreads();

    const int r = ((base * 4) & n_mask) & (HOP - 1);   // invariant across u
    const f32x4 wi = reinterpret_cast<const f32x4*>(wt)[r >> 2];

#pragma unroll
    for (int u = 0; u < UNROLL; ++u) {
        const int pos = ((base + u * BLOCK) * 4) & n_mask;
        const int blk = pos >> 8;            // wave-uniform
        f32x4 w;
        if (blk >= 3 && blk <= kmax) {
            w = wi;                          // interior: all 4 terms
        } else {
            // edge blocks (6 of 8192 per row), wave-uniform branch
            float e[4] = {0.f, 0.f, 0.f, 0.f};
#pragma unroll
            for (int m = 0; m < 4; ++m) {
                if (blk >= m && (blk - m) <= kmax) {
#pragma unroll
                    for (int j = 0; j < 4; ++j)
                        e[j] += aw[r + j + m * HOP] * sw[r + j + m * HOP];
                }
            }
            w = f32x4{e[0], e[1], e[2], e[3]};
        }
        y4[base + u * BLOCK] = xv[u] * w;    // plain store
    }
}

extern "C" void kernel_launch(void* const* d_in, const int* in_sizes, int n_in,
                              void* d_out, int out_size, void* d_ws, size_t ws_size,
                              hipStream_t stream) {
    const float* x  = (const float*)d_in[0];
    const float* aw = (const float*)d_in[1];
    const float* sw = (const float*)d_in[2];

    const int N = 1 << 21;                  // samples per row (power of two)
    const int total4 = out_size / 4;        // 8,388,608 float4s
    const int kmax = (N - SEG) / HOP;       // 8188

    dim3 block(BLOCK);
    dim3 grid(total4 / (BLOCK * UNROLL));   // 4096 one-shot blocks, 32 KB each

    SegmenterTensorFlow_28698971472345_kernel<<<grid, block, 0, stream>>>(
        (const f32x4*)x, aw, sw, (f32x4*)d_out, N - 1, kmax);
}

// Round 8
// 221.960 us; speedup vs baseline: 1.0396x; 1.0396x over previous
//
#include <hip/hip_runtime.h>

#define HOP 256
#define SEG 1024
#define BLOCK 256

typedef float f32x4 __attribute__((ext_vector_type(4)));

// y[b,i] = x[b,i] * W[pos],  W[pos] = sum_{m=0..3} aw[r+256m]*sw[r+256m]
//   r = pos & 255, blk = pos >> 8, term m included iff blk >= m && blk-m <= kmax.
//
// FINAL (revert to round-5 measured-best, 221.9us bench / ~74us per dispatch).
// Session evidence:
//  - One-shot copy-shaped structure + per-block LDS weight table is the floor.
//  - Controls: precomputed-table copy-shape (R6) identical -> instructions free;
//    contiguous 8-deep ILP (R7) and strided ILP (R3) both slower; NT store
//    regression; NT load neutral (kept: measured-best binary had it).
//  - Floor cause: x+y = 256 MiB = L3 capacity; y's write-allocations evict
//    half of x (FETCH = x/2 stably) -> 128B-granular hit/miss read interleave
//    caps mixed throughput at ~2.6 TB/s. No kernel-side knob remains.
__global__ __launch_bounds__(BLOCK) void SegmenterTensorFlow_28698971472345_kernel(
    const f32x4* __restrict__ x4,
    const float* __restrict__ aw,
    const float* __restrict__ sw,
    f32x4* __restrict__ y4,
    int n_mask,          // N - 1 (N power of two)
    int kmax)            // num_segments - 1 = 8188
{
    const int tid = blockIdx.x * BLOCK + threadIdx.x;

    // Bulk load first; everything below overlaps its latency.
    const f32x4 xv = __builtin_nontemporal_load(&x4[tid]);

    // Combined-window table for this block: wt[r] = sum_m aw[r+256m]*sw[r+256m].
    __shared__ float wt[HOP];
    {
        const int i = threadIdx.x;          // 256 threads <-> 256 entries
        float acc = 0.f;
#pragma unroll
        for (int m = 0; m < 4; ++m)
            acc += aw[i + m * HOP] * sw[i + m * HOP];
        wt[i] = acc;
    }
    __syncthreads();

    const int pos = (tid * 4) & n_mask;     // position within the row
    const int blk = pos >> 8;               // wave-uniform (64 lanes * 4 = HOP)
    const int r   = pos & (HOP - 1);

    f32x4 w;
    if (blk >= 3 && blk <= kmax) {
        // interior: all 4 terms -> straight table lookup (ds_read_b128)
        w = reinterpret_cast<const f32x4*>(wt)[r >> 2];
    } else {
        // edge blocks (6 of 8192 per row), wave-uniform branch: direct sum
        float e[4] = {0.f, 0.f, 0.f, 0.f};
#pragma unroll
        for (int m = 0; m < 4; ++m) {
            if (blk >= m && (blk - m) <= kmax) {
#pragma unroll
                for (int j = 0; j < 4; ++j)
                    e[j] += aw[r + j + m * HOP] * sw[r + j + m * HOP];
            }
        }
        w = f32x4{e[0], e[1], e[2], e[3]};
    }

    y4[tid] = xv * w;   // plain store (NT-store was a measured regression)
}

extern "C" void kernel_launch(void* const* d_in, const int* in_sizes, int n_in,
                              void* d_out, int out_size, void* d_ws, size_t ws_size,
                              hipStream_t stream) {
    const float* x  = (const float*)d_in[0];
    const float* aw = (const float*)d_in[1];
    const float* sw = (const float*)d_in[2];

    const int N = 1 << 21;                  // samples per row (power of two)
    const int total4 = out_size / 4;        // 8,388,608 float4s
    const int kmax = (N - SEG) / HOP;       // 8188

    dim3 block(BLOCK);
    dim3 grid(total4 / BLOCK);              // 32768 one-shot blocks

    SegmenterTensorFlow_28698971472345_kernel<<<grid, block, 0, stream>>>(
        (const f32x4*)x, aw, sw, (f32x4*)d_out, N - 1, kmax);
}